// Round 5
// baseline (9714.683 us; speedup 1.0000x reference)
//
#include <hip/hip_runtime.h>

#define B_ 128
#define T_ 2048
#define H_ 128
#define NI_ 64
#define NO_ 64

typedef short s16x8 __attribute__((ext_vector_type(8)));
typedef float f32x4 __attribute__((ext_vector_type(4)));

__device__ __forceinline__ unsigned short f2bf(float f) {
  unsigned int u = __float_as_uint(f);
  u += 0x7fffu + ((u >> 16) & 1u);
  return (unsigned short)(u >> 16);
}
__device__ __forceinline__ f32x4 mfma16(s16x8 a, s16x8 b, f32x4 c) {
  return __builtin_amdgcn_mfma_f32_16x16x32_bf16(a, b, c, 0, 0, 0);
}
// load 8 consecutive f32 -> bf16 fragment (k = +0..7)
__device__ __forceinline__ s16x8 load8(const float* p) {
  float4 a = *reinterpret_cast<const float4*>(p);
  float4 b = *reinterpret_cast<const float4*>(p + 4);
  s16x8 r;
  r[0] = (short)f2bf(a.x); r[1] = (short)f2bf(a.y);
  r[2] = (short)f2bf(a.z); r[3] = (short)f2bf(a.w);
  r[4] = (short)f2bf(b.x); r[5] = (short)f2bf(b.y);
  r[6] = (short)f2bf(b.z); r[7] = (short)f2bf(b.w);
  return r;
}
__device__ __forceinline__ s16x8 cvt8(float4 a, float4 b) {
  s16x8 v;
  v[0] = (short)f2bf(a.x); v[1] = (short)f2bf(a.y);
  v[2] = (short)f2bf(a.z); v[3] = (short)f2bf(a.w);
  v[4] = (short)f2bf(b.x); v[5] = (short)f2bf(b.y);
  v[6] = (short)f2bf(b.z); v[7] = (short)f2bf(b.w);
  return v;
}

// Transposed formulation: y^T = W * h^T. A-operand = W rows (gate dims),
// B-operand = h^T / X^T (cols = 16 batch rows). C: col=lane&15=batch,
// row=4*lg+r = gate dim -> gates are fully elementwise IN-REGISTER.
// Wave w owns hdim tile [16w,16w+16): computes hp/r/z/n rows for that tile.
// One WG = 16 batch rows, 8 waves, ONE barrier per step (double-buffered h).
__global__ __launch_bounds__(512, 2) void gru_seq_kernel(
    const float* __restrict__ X, const float* __restrict__ h0,
    const float* __restrict__ W_ih, const float* __restrict__ W_hh,
    const float* __restrict__ b_ih, const float* __restrict__ b_hh,
    const float* __restrict__ W_rec, const float* __restrict__ W_out,
    const float* __restrict__ b_out,
    float* __restrict__ out, float* __restrict__ hidden)
{
  __shared__ __align__(16) unsigned short chunk[128][136];  // prologue W_comb staging
  __shared__ __align__(16) unsigned short hlds[2][2048];    // h bf16 [batch][hdim], XOR-swizzled

  const int tid = threadIdx.x;
  const int w   = tid >> 6;        // wave 0..7 -> hdim tile
  const int l15 = tid & 15;
  const int lg  = (tid >> 4) & 3;
  const int r0  = blockIdx.x * 16; // batch base

  // ---- prologue ----
  // hp A-frags: W_rec rows 16w+l15
  s16x8 am_hp[4];
  #pragma unroll
  for (int kt = 0; kt < 4; ++kt)
    am_hp[kt] = load8(&W_rec[(size_t)(16 * w + l15) * H_ + 32 * kt + 8 * lg]);

  // W_comb = W_hh @ W_rec (384x128), 3 chunks of 128 rows, all waves help.
  // After chunk c (gate c block), every wave grabs its A-frags (rows 16w+l15).
  s16x8 am_g[3][4];
  for (int c = 0; c < 3; ++c) {
    s16x8 afr[4];
    #pragma unroll
    for (int kt = 0; kt < 4; ++kt)
      afr[kt] = load8(&W_hh[(size_t)(128 * c + 16 * w + l15) * H_ + 32 * kt + 8 * lg]);
    f32x4 D[8];
    #pragma unroll
    for (int nt = 0; nt < 8; ++nt) {
      D[nt] = (f32x4){0.f, 0.f, 0.f, 0.f};
      #pragma unroll
      for (int kt = 0; kt < 4; ++kt) {
        s16x8 bfr;
        int kb = 32 * kt + 8 * lg, n = 16 * nt + l15;
        #pragma unroll
        for (int j = 0; j < 8; ++j)
          bfr[j] = (short)f2bf(W_rec[(size_t)(kb + j) * H_ + n]);
        D[nt] = mfma16(afr[kt], bfr, D[nt]);
      }
    }
    #pragma unroll
    for (int nt = 0; nt < 8; ++nt)
      #pragma unroll
      for (int r = 0; r < 4; ++r)
        chunk[16 * w + 4 * lg + r][16 * nt + l15] = f2bf(D[nt][r]);
    __syncthreads();
    #pragma unroll
    for (int kt = 0; kt < 4; ++kt)
      am_g[c][kt] = *reinterpret_cast<const s16x8*>(&chunk[16 * w + l15][32 * kt + 8 * lg]);
    __syncthreads();
  }

  // x-side A-frags: W_ih rows (gate block g, row 16w+l15)
  s16x8 ax_g[3][2];
  #pragma unroll
  for (int g = 0; g < 3; ++g)
    #pragma unroll
    for (int kt = 0; kt < 2; ++kt)
      ax_g[g][kt] = load8(&W_ih[(size_t)(128 * g + 16 * w + l15) * NI_ + 32 * kt + 8 * lg]);

  // out-proj A-frags (waves 0..3 own the 4 out tiles)
  s16x8 ao[4];
  f32x4 bo = (f32x4){0.f, 0.f, 0.f, 0.f};
  if (w < 4) {
    #pragma unroll
    for (int kt = 0; kt < 4; ++kt)
      ao[kt] = load8(&W_out[(size_t)(16 * w + l15) * H_ + 32 * kt + 8 * lg]);
    #pragma unroll
    for (int r = 0; r < 4; ++r)
      bo[r] = b_out[16 * w + 4 * lg + r];
  }

  // gate biases, indexed by ROW (gate dim d = 16w+4lg+r)
  f32x4 br, bz, bnh, bnx;
  #pragma unroll
  for (int r = 0; r < 4; ++r) {
    int d = 16 * w + 4 * lg + r;
    br[r]  = b_ih[d] + b_hh[d];
    bz[r]  = b_ih[H_ + d] + b_hh[H_ + d];
    bnx[r] = b_ih[2 * H_ + d];
    bnh[r] = b_hh[2 * H_ + d];
  }

  // h0 B-frags: lane l15 = batch col, k = hdim 32kt+8lg+j
  s16x8 ha[4];
  #pragma unroll
  for (int kt = 0; kt < 4; ++kt)
    ha[kt] = load8(&h0[(size_t)(r0 + l15) * H_ + 32 * kt + 8 * lg]);

  // X B-frags (all waves, identical addrs -> L1 hits), prefetch t=0
  const float* xptr = &X[(size_t)(r0 + l15) * T_ * NI_];
  const float* xpf  = xptr + NI_;   // prefetch pointer (t+1)
  float4 xt[4];
  s16x8 xb[2];
  #pragma unroll
  for (int kt = 0; kt < 2; ++kt) {
    xt[2 * kt]     = *reinterpret_cast<const float4*>(xptr + 32 * kt + 8 * lg);
    xt[2 * kt + 1] = *reinterpret_cast<const float4*>(xptr + 32 * kt + 8 * lg + 4);
  }
  #pragma unroll
  for (int kt = 0; kt < 2; ++kt)
    xb[kt] = cvt8(xt[2 * kt], xt[2 * kt + 1]);

  float* hidp = hidden + (size_t)(r0 + l15) * T_ * H_ + 16 * w + 4 * lg;
  float* outp = out + (size_t)(r0 + l15) * T_ * NO_ + 16 * w + 4 * lg;
  char* hbase = reinterpret_cast<char*>(hlds);
  const unsigned int wsw = (unsigned)(l15 & 7) << 4;  // XOR swizzle (G4 fix)
  const unsigned int waddr = ((unsigned)(l15 * 256 + (16 * w + 4 * lg) * 2)) ^ wsw;

  #pragma unroll 1
  for (int t = 0; t < T_; ++t) {
    // issue X prefetch for t+1 (consumed at loop bottom -> full-iter cover)
    if (t + 1 < T_) {
      #pragma unroll
      for (int kt = 0; kt < 2; ++kt) {
        xt[2 * kt]     = *reinterpret_cast<const float4*>(xpf + 32 * kt + 8 * lg);
        xt[2 * kt + 1] = *reinterpret_cast<const float4*>(xpf + 32 * kt + 8 * lg + 4);
      }
      xpf += NI_;
    }
    // out-proj for t-1 (ha == h_{t-1}; reuses the same B-frags)
    if (w < 4 && t > 0) {
      f32x4 oa = bo;
      #pragma unroll
      for (int kt = 0; kt < 4; ++kt)
        oa = mfma16(ao[kt], ha[kt], oa);
      *reinterpret_cast<float4*>(outp) = make_float4(oa[0], oa[1], oa[2], oa[3]);
      outp += NO_;
    }
    // y^T tiles: hp / r / z / n-h-side (K=128), + x-side (K=64)
    f32x4 ahp = (f32x4){0.f, 0.f, 0.f, 0.f};
    f32x4 ar = br, az = bz, anh = bnh, anx = bnx;
    #pragma unroll
    for (int kt = 0; kt < 4; ++kt) {
      ahp = mfma16(am_hp[kt],   ha[kt], ahp);
      ar  = mfma16(am_g[0][kt], ha[kt], ar);
      az  = mfma16(am_g[1][kt], ha[kt], az);
      anh = mfma16(am_g[2][kt], ha[kt], anh);
    }
    #pragma unroll
    for (int kt = 0; kt < 2; ++kt) {
      ar  = mfma16(ax_g[0][kt], xb[kt], ar);
      az  = mfma16(ax_g[1][kt], xb[kt], az);
      anx = mfma16(ax_g[2][kt], xb[kt], anx);
    }
    // gates: fully in-register, matching (hdim,batch) lanes
    float hn[4];
    #pragma unroll
    for (int q = 0; q < 4; ++q) {
      float rg = 1.f / (1.f + __expf(-ar[q]));
      float zg = 1.f / (1.f + __expf(-az[q]));
      float a2 = anx[q] + rg * anh[q];
      float e2 = __expf(2.f * a2);
      float ng = (e2 - 1.f) / (e2 + 1.f);  // tanh
      hn[q] = (1.f - zg) * ng + zg * ahp[q];
    }
    *reinterpret_cast<float4*>(hidp) = make_float4(hn[0], hn[1], hn[2], hn[3]);
    hidp += H_;
    // h -> LDS (double-buffered, one ds_write_b64, swizzled)
    unsigned int p0 = (unsigned)f2bf(hn[0]) | ((unsigned)f2bf(hn[1]) << 16);
    unsigned int p1 = (unsigned)f2bf(hn[2]) | ((unsigned)f2bf(hn[3]) << 16);
    char* hb = hbase + ((t & 1) << 12);
    *reinterpret_cast<uint2*>(hb + waddr) = make_uint2(p0, p1);
    // convert prefetched X for t+1 (off the post-barrier critical path)
    if (t + 1 < T_) {
      #pragma unroll
      for (int kt = 0; kt < 2; ++kt)
        xb[kt] = cvt8(xt[2 * kt], xt[2 * kt + 1]);
    }
    __syncthreads();  // the ONLY barrier per step
    // reload h B-frags (4x ds_read_b128, same swizzle -> ~conflict-free)
    #pragma unroll
    for (int kt = 0; kt < 4; ++kt) {
      unsigned int ra = ((unsigned)(l15 * 256 + 64 * kt + 16 * lg)) ^ wsw;
      ha[kt] = *reinterpret_cast<const s16x8*>(hb + ra);
    }
  }
  // final out-proj (t = T-1)
  if (w < 4) {
    f32x4 oa = bo;
    #pragma unroll
    for (int kt = 0; kt < 4; ++kt)
      oa = mfma16(ao[kt], ha[kt], oa);
    *reinterpret_cast<float4*>(outp) = make_float4(oa[0], oa[1], oa[2], oa[3]);
  }
}

extern "C" void kernel_launch(void* const* d_in, const int* in_sizes, int n_in,
                              void* d_out, int out_size, void* d_ws, size_t ws_size,
                              hipStream_t stream) {
  const float* X     = (const float*)d_in[0];
  const float* h0    = (const float*)d_in[1];
  const float* W_ih  = (const float*)d_in[2];
  const float* W_hh  = (const float*)d_in[3];
  const float* b_ih  = (const float*)d_in[4];
  const float* b_hh  = (const float*)d_in[5];
  const float* W_rec = (const float*)d_in[6];
  const float* W_out = (const float*)d_in[7];
  const float* b_out = (const float*)d_in[8];
  float* out    = (float*)d_out;                // [B,T,NO]
  float* hidden = out + (size_t)B_ * T_ * NO_;  // [B,T,H]
  gru_seq_kernel<<<dim3(8), dim3(512), 0, stream>>>(X, h0, W_ih, W_hh, b_ih, b_hh,
                                                    W_rec, W_out, b_out, out, hidden);
}

// Round 8
// 8984.984 us; speedup vs baseline: 1.0812x; 1.0812x over previous
//
#include <hip/hip_runtime.h>

#define B_ 128
#define T_ 2048
#define H_ 128
#define NI_ 64
#define NO_ 64

typedef short s16x8 __attribute__((ext_vector_type(8)));
typedef float f32x4 __attribute__((ext_vector_type(4)));

__device__ __forceinline__ unsigned short f2bf(float f) {
  unsigned int u = __float_as_uint(f);
  u += 0x7fffu + ((u >> 16) & 1u);
  return (unsigned short)(u >> 16);
}
__device__ __forceinline__ float bf2f(unsigned short u) {
  return __uint_as_float((unsigned int)u << 16);
}
__device__ __forceinline__ f32x4 mfma16(s16x8 a, s16x8 b, f32x4 c) {
  return __builtin_amdgcn_mfma_f32_16x16x32_bf16(a, b, c, 0, 0, 0);
}
// load 8 consecutive f32 -> bf16 fragment (k = +0..7)
__device__ __forceinline__ s16x8 load8(const float* p) {
  float4 a = *reinterpret_cast<const float4*>(p);
  float4 b = *reinterpret_cast<const float4*>(p + 4);
  s16x8 r;
  r[0] = (short)f2bf(a.x); r[1] = (short)f2bf(a.y);
  r[2] = (short)f2bf(a.z); r[3] = (short)f2bf(a.w);
  r[4] = (short)f2bf(b.x); r[5] = (short)f2bf(b.y);
  r[6] = (short)f2bf(b.z); r[7] = (short)f2bf(b.w);
  return r;
}

// ---------------- xg_pre: xg[t][g][b][dd] (bf16) = X @ W_ih^T + b_ih ----------------
// block = one timestep t; 4 waves; wave w covers batch-tiles {2w, 2w+1}.
__global__ __launch_bounds__(256) void xg_pre_kernel(
    const float* __restrict__ X, const float* __restrict__ W_ih,
    const float* __restrict__ b_ih, unsigned short* __restrict__ xg)
{
  const int t   = blockIdx.x;
  const int tid = threadIdx.x;
  const int w   = tid >> 6;
  const int l15 = tid & 15;
  const int lg  = (tid >> 4) & 3;

  #pragma unroll
  for (int bi = 0; bi < 2; ++bi) {
    const int bt = 2 * w + bi;
    const int b  = bt * 16 + l15;
    // B-frags: X[b][t][k], k = 32kt+8lg+j
    s16x8 xb[2];
    #pragma unroll
    for (int kt = 0; kt < 2; ++kt)
      xb[kt] = load8(&X[((size_t)b * T_ + t) * NI_ + 32 * kt + 8 * lg]);
    for (int dtile = 0; dtile < 24; ++dtile) {
      // A-frags: W_ih rows dtile*16 + l15
      s16x8 af[2];
      #pragma unroll
      for (int kt = 0; kt < 2; ++kt)
        af[kt] = load8(&W_ih[(size_t)(dtile * 16 + l15) * NI_ + 32 * kt + 8 * lg]);
      float4 bias = *reinterpret_cast<const float4*>(&b_ih[dtile * 16 + 4 * lg]);
      f32x4 acc = (f32x4){bias.x, bias.y, bias.z, bias.w};
      acc = mfma16(af[0], xb[0], acc);
      acc = mfma16(af[1], xb[1], acc);
      const int g  = dtile >> 3;
      const int dd = (dtile & 7) * 16 + 4 * lg;
      unsigned int p0 = (unsigned)f2bf(acc[0]) | ((unsigned)f2bf(acc[1]) << 16);
      unsigned int p1 = (unsigned)f2bf(acc[2]) | ((unsigned)f2bf(acc[3]) << 16);
      *reinterpret_cast<uint2*>(&xg[((size_t)(t * 3 + g) * B_ + b) * H_ + dd]) =
          make_uint2(p0, p1);
    }
  }
}

// ---------------- sequential GRU ----------------
// Transposed: y^T = W * h^T; gates fully in-register. Wave w owns hdim tile
// [16w,16w+16). h LDS layout = round-1-PROVEN fragment-major:
//   byte(d,b) = (d>>3)*256 + b*16 + (d&7)*2, XOR-swizzled by block bits.
__global__ __launch_bounds__(512, 1) void gru_seq_kernel(
    const float* __restrict__ h0,
    const float* __restrict__ W_hh, const float* __restrict__ b_hh,
    const float* __restrict__ W_rec, const float* __restrict__ W_out,
    const float* __restrict__ b_out, const unsigned short* __restrict__ xg,
    float* __restrict__ out, float* __restrict__ hidden)
{
  __shared__ __align__(16) unsigned short chunk[128][136];  // prologue staging
  __shared__ __align__(16) unsigned short hfm[2][2048];     // h bf16 fragment-major

  const int tid = threadIdx.x;
  const int w   = tid >> 6;
  const int l15 = tid & 15;
  const int lg  = (tid >> 4) & 3;
  const int r0  = blockIdx.x * 16;

  // hp A-frags: W_rec rows 16w+l15
  s16x8 am_hp[4];
  #pragma unroll
  for (int kt = 0; kt < 4; ++kt)
    am_hp[kt] = load8(&W_rec[(size_t)(16 * w + l15) * H_ + 32 * kt + 8 * lg]);

  // W_comb = W_hh @ W_rec, 3 chunks of 128 rows
  s16x8 am_g[3][4];
  for (int c = 0; c < 3; ++c) {
    s16x8 afr[4];
    #pragma unroll
    for (int kt = 0; kt < 4; ++kt)
      afr[kt] = load8(&W_hh[(size_t)(128 * c + 16 * w + l15) * H_ + 32 * kt + 8 * lg]);
    f32x4 D[8];
    #pragma unroll
    for (int nt = 0; nt < 8; ++nt) {
      D[nt] = (f32x4){0.f, 0.f, 0.f, 0.f};
      #pragma unroll
      for (int kt = 0; kt < 4; ++kt) {
        s16x8 bfr;
        int kb = 32 * kt + 8 * lg, n = 16 * nt + l15;
        #pragma unroll
        for (int j = 0; j < 8; ++j)
          bfr[j] = (short)f2bf(W_rec[(size_t)(kb + j) * H_ + n]);
        D[nt] = mfma16(afr[kt], bfr, D[nt]);
      }
    }
    #pragma unroll
    for (int nt = 0; nt < 8; ++nt)
      #pragma unroll
      for (int r = 0; r < 4; ++r)
        chunk[16 * w + 4 * lg + r][16 * nt + l15] = f2bf(D[nt][r]);
    __syncthreads();
    #pragma unroll
    for (int kt = 0; kt < 4; ++kt)
      am_g[c][kt] = *reinterpret_cast<const s16x8*>(&chunk[16 * w + l15][32 * kt + 8 * lg]);
    __syncthreads();
  }

  // out-proj A-frags (waves 0..3)
  s16x8 ao[4];
  f32x4 bo = (f32x4){0.f, 0.f, 0.f, 0.f};
  if (w < 4) {
    #pragma unroll
    for (int kt = 0; kt < 4; ++kt)
      ao[kt] = load8(&W_out[(size_t)(16 * w + l15) * H_ + 32 * kt + 8 * lg]);
    #pragma unroll
    for (int r = 0; r < 4; ++r)
      bo[r] = b_out[16 * w + 4 * lg + r];
  }

  // h-side biases only (x-side biases live in xg)
  f32x4 br, bz, bnh;
  #pragma unroll
  for (int r = 0; r < 4; ++r) {
    int d = 16 * w + 4 * lg + r;
    br[r]  = b_hh[d];
    bz[r]  = b_hh[H_ + d];
    bnh[r] = b_hh[2 * H_ + d];
  }

  // h0 B-frags
  s16x8 ha[4];
  #pragma unroll
  for (int kt = 0; kt < 4; ++kt)
    ha[kt] = load8(&h0[(size_t)(r0 + l15) * H_ + 32 * kt + 8 * lg]);

  // xg pointers: lane reads 4 bf16 (8B) per gate at (b=r0+l15, dd=16w+4lg)
  const unsigned short* xgbase =
      xg + ((size_t)(r0 + l15)) * H_ + (16 * w + 4 * lg);
  const size_t gstride = (size_t)B_ * H_;        // gate stride within a t
  const size_t tstride = 3 * gstride;            // t stride
  uint2 xgC[3], xgN[3];
  #pragma unroll
  for (int g = 0; g < 3; ++g)
    xgC[g] = *reinterpret_cast<const uint2*>(xgbase + g * gstride);

  float* hidp = hidden + (size_t)(r0 + l15) * T_ * H_ + 16 * w + 4 * lg;
  float* outp = out + (size_t)(r0 + l15) * T_ * NO_ + 16 * w + 4 * lg;
  char* hbase = reinterpret_cast<char*>(hfm);
  // write: d0 = 16w+4lg -> block bb=d0>>3; byte = bb*256 + l15*16 + (d0&7)*2
  const int d0 = 16 * w + 4 * lg;
  const unsigned int bbw = (unsigned)(d0 >> 3);
  const unsigned int waddr =
      (bbw * 256 + (unsigned)l15 * 16 + (unsigned)(d0 & 7) * 2) ^ ((bbw & 7u) << 4);

  #pragma unroll 1
  for (int t = 0; t < T_; ++t) {
    // distance-1 xg prefetch (t+1)
    if (t + 1 < T_) {
      const unsigned short* p = xgbase + (size_t)(t + 1) * tstride;
      #pragma unroll
      for (int g = 0; g < 3; ++g)
        xgN[g] = *reinterpret_cast<const uint2*>(p + g * gstride);
    }
    // out-proj for t-1 (ha == h_{t-1})
    if (w < 4 && t > 0) {
      f32x4 oa = bo;
      #pragma unroll
      for (int kt = 0; kt < 4; ++kt)
        oa = mfma16(ao[kt], ha[kt], oa);
      *reinterpret_cast<float4*>(outp) = make_float4(oa[0], oa[1], oa[2], oa[3]);
      outp += NO_;
    }
    // h-side projections: hp / r / z / n (K=128), 4-deep chains
    f32x4 ahp = (f32x4){0.f, 0.f, 0.f, 0.f};
    f32x4 ar = br, az = bz, anh = bnh;
    #pragma unroll
    for (int kt = 0; kt < 4; ++kt) {
      ahp = mfma16(am_hp[kt],   ha[kt], ahp);
      ar  = mfma16(am_g[0][kt], ha[kt], ar);
      az  = mfma16(am_g[1][kt], ha[kt], az);
      anh = mfma16(am_g[2][kt], ha[kt], anh);
    }
    // gates: in-register; x-side comes from xg (bf16)
    float xr[4], xz[4], xn[4];
    xr[0] = bf2f((unsigned short)(xgC[0].x & 0xffff)); xr[1] = bf2f((unsigned short)(xgC[0].x >> 16));
    xr[2] = bf2f((unsigned short)(xgC[0].y & 0xffff)); xr[3] = bf2f((unsigned short)(xgC[0].y >> 16));
    xz[0] = bf2f((unsigned short)(xgC[1].x & 0xffff)); xz[1] = bf2f((unsigned short)(xgC[1].x >> 16));
    xz[2] = bf2f((unsigned short)(xgC[1].y & 0xffff)); xz[3] = bf2f((unsigned short)(xgC[1].y >> 16));
    xn[0] = bf2f((unsigned short)(xgC[2].x & 0xffff)); xn[1] = bf2f((unsigned short)(xgC[2].x >> 16));
    xn[2] = bf2f((unsigned short)(xgC[2].y & 0xffff)); xn[3] = bf2f((unsigned short)(xgC[2].y >> 16));
    float hn[4];
    #pragma unroll
    for (int q = 0; q < 4; ++q) {
      float rg = 1.f / (1.f + __expf(-(ar[q] + xr[q])));
      float zg = 1.f / (1.f + __expf(-(az[q] + xz[q])));
      float a2 = xn[q] + rg * anh[q];
      float e2 = __expf(2.f * a2);
      float ng = (e2 - 1.f) / (e2 + 1.f);  // tanh
      hn[q] = (1.f - zg) * ng + zg * ahp[q];
    }
    *reinterpret_cast<float4*>(hidp) = make_float4(hn[0], hn[1], hn[2], hn[3]);
    hidp += H_;
    // h -> LDS (round-1-proven fragment-major layout, 8B write)
    unsigned int p0 = (unsigned)f2bf(hn[0]) | ((unsigned)f2bf(hn[1]) << 16);
    unsigned int p1 = (unsigned)f2bf(hn[2]) | ((unsigned)f2bf(hn[3]) << 16);
    char* hb = hbase + ((t & 1) << 12);
    *reinterpret_cast<uint2*>(hb + waddr) = make_uint2(p0, p1);
    // rotate xg prefetch
    xgC[0] = xgN[0]; xgC[1] = xgN[1]; xgC[2] = xgN[2];
    __syncthreads();  // ONE barrier per step
    // reload h B-frags: byte = (kt*4+lg)*256 + l15*16, same swizzle
    #pragma unroll
    for (int kt = 0; kt < 4; ++kt) {
      unsigned int bb = (unsigned)(kt * 4 + lg);
      unsigned int ra = (bb * 256 + (unsigned)l15 * 16) ^ ((bb & 7u) << 4);
      ha[kt] = *reinterpret_cast<const s16x8*>(hb + ra);
    }
  }
  // final out-proj (t = T-1)
  if (w < 4) {
    f32x4 oa = bo;
    #pragma unroll
    for (int kt = 0; kt < 4; ++kt)
      oa = mfma16(ao[kt], ha[kt], oa);
    *reinterpret_cast<float4*>(outp) = make_float4(oa[0], oa[1], oa[2], oa[3]);
  }
}

extern "C" void kernel_launch(void* const* d_in, const int* in_sizes, int n_in,
                              void* d_out, int out_size, void* d_ws, size_t ws_size,
                              hipStream_t stream) {
  const float* X     = (const float*)d_in[0];
  const float* h0    = (const float*)d_in[1];
  const float* W_ih  = (const float*)d_in[2];
  const float* W_hh  = (const float*)d_in[3];
  const float* b_ih  = (const float*)d_in[4];
  const float* b_hh  = (const float*)d_in[5];
  const float* W_rec = (const float*)d_in[6];
  const float* W_out = (const float*)d_in[7];
  const float* b_out = (const float*)d_in[8];
  float* out    = (float*)d_out;                // [B,T,NO]
  float* hidden = out + (size_t)B_ * T_ * NO_;  // [B,T,H]
  unsigned short* xg = (unsigned short*)d_ws;   // [T][3][B][H] bf16 = 201 MB

  xg_pre_kernel<<<dim3(T_), dim3(256), 0, stream>>>(X, W_ih, b_ih, xg);
  gru_seq_kernel<<<dim3(8), dim3(512), 0, stream>>>(h0, W_hh, b_hh, W_rec, W_out,
                                                    b_out, xg, out, hidden);
}